// Round 3
// baseline (116.457 us; speedup 1.0000x reference)
//
#include <hip/hip_runtime.h>

#define B_   64
#define T_   2000
#define RNN_ 1024
#define EMB_ 512
#define ATT_ 128
#define CH_  8
#define K_   21
#define PL_  11
#define GSZ  168   // CH_*K_
#define CHK  64    // T-chunk per fused block
#define NCHK 32    // ceil(T/CHK)

typedef float vf4 __attribute__((ext_vector_type(4)));

__device__ __forceinline__ float fast_tanh(float x) {
    float ax = fabsf(x);
    float e  = __expf(2.0f * ax);
    float t  = 1.0f - 2.0f / (e + 1.0f);
    return copysignf(t, x);
}

// ---- kernel 1: G = tanh(q @ W_w^T + W_b) @ V_w^T  -> [B,168] ----
__global__ __launch_bounds__(256) void k_gen_dyn(
    const float* __restrict__ q, const float* __restrict__ Ww,
    const float* __restrict__ Wb, const float* __restrict__ Vw,
    float* __restrict__ G)
{
    __shared__ float sq[RNN_];
    __shared__ float part[256];
    __shared__ float sh[ATT_];
    const int b = blockIdx.x, tid = threadIdx.x;
    for (int i = tid; i < RNN_; i += 256) sq[i] = q[b * RNN_ + i];
    __syncthreads();
    {
        const int row = tid & 127, half = tid >> 7;        // 2-way K split
        const float4* wr = reinterpret_cast<const float4*>(Ww + row * RNN_ + half * (RNN_ / 2));
        const float4* qr = reinterpret_cast<const float4*>(sq + half * (RNN_ / 2));
        float acc = 0.f;
        #pragma unroll 8
        for (int i = 0; i < RNN_ / 8; ++i) {
            float4 w4 = wr[i], q4 = qr[i];
            acc += w4.x * q4.x + w4.y * q4.y + w4.z * q4.z + w4.w * q4.w;
        }
        part[tid] = acc;
    }
    __syncthreads();
    if (tid < ATT_) sh[tid] = fast_tanh(part[tid] + part[tid + 128] + Wb[tid]);
    __syncthreads();
    for (int o = tid; o < GSZ; o += 256) {
        const float4* vr = reinterpret_cast<const float4*>(Vw + o * ATT_);
        const float4* hr = reinterpret_cast<const float4*>(sh);
        float acc = 0.f;
        #pragma unroll 8
        for (int i = 0; i < ATT_ / 4; ++i) {
            float4 v4 = vr[i], h4 = hr[i];
            acc += v4.x * h4.x + v4.y * h4.y + v4.z * h4.z + v4.w * h4.w;
        }
        G[b * GSZ + o] = acc;
    }
}

// ---- kernel 2: fused energy + chunk-local softmax + partial context ----
__global__ __launch_bounds__(256) void k_fused(
    const float* __restrict__ a,  const float* __restrict__ G,
    const float* __restrict__ Fw, const float* __restrict__ Uw,
    const float* __restrict__ Tw, const float* __restrict__ Tb,
    const float* __restrict__ vw, const float* __restrict__ P,
    const unsigned char* __restrict__ mask, const float* __restrict__ mem,
    float* __restrict__ wout,   // [B,T]   unnormalized p = exp(e - m_chunk)
    float* __restrict__ ctxp,   // [B,NCHK,EMB] partial contexts
    float* __restrict__ mred,   // [B,NCHK] chunk maxes
    float* __restrict__ sred)   // [B,NCHK] chunk sums
{
    __shared__ float sA[CHK + K_ - 1];   // 84: alignment window with halo
    __shared__ float sFG[K_ * 16];       // [k][16]: c<8 = F_w[c][k], c>=8 = G[b][(c-8)*21+k]
    __shared__ float sUT[ATT_ * 16];     // [d][16]: c<8 = U_w[d][c], c>=8 = T_w[d][c-8]
    __shared__ float sTb[ATT_], sV[ATT_], sPr[PL_];
    __shared__ float sQ[4 * CHK];        // quarter-partials of energy MLP
    __shared__ float sE[CHK];            // e, then p
    __shared__ vf4   sCtx4[2][EMB_ / 4]; // rowpair partial contexts

    const int b = blockIdx.x, chunk = blockIdx.y, tid = threadIdx.x;
    const int t0 = chunk * CHK;
    const int nvalid = min(CHK, T_ - t0);
    const int base = t0 - (K_ - 1) / 2;

    for (int j = tid; j < CHK + K_ - 1; j += 256) {
        int idx = base + j;
        sA[j] = (idx >= 0 && idx < T_) ? a[b * T_ + idx] : 0.f;
    }
    for (int j = tid; j < 2 * GSZ; j += 256) {
        if (j < GSZ) sFG[(j % K_) * 16 + (j / K_)] = Fw[j];
        else { int jj = j - GSZ; sFG[(jj % K_) * 16 + 8 + (jj / K_)] = G[b * GSZ + jj]; }
    }
    for (int j = tid; j < ATT_ * CH_; j += 256) {
        int d = j >> 3, c = j & 7;
        sUT[d * 16 + c]     = Uw[j];
        sUT[d * 16 + 8 + c] = Tw[j];
    }
    if (tid < ATT_) { sTb[tid] = Tb[tid]; sV[tid] = vw[tid]; }
    if (tid < PL_)  sPr[tid] = P[tid];
    __syncthreads();

    // ---- energies: thread = (t = tid&63, q = tid>>6 handles 32 of 128 dims) ----
    {
        const int t = tid & (CHK - 1);
        const int qq = tid >> 6;
        float fg[16];
        #pragma unroll
        for (int i = 0; i < 16; ++i) fg[i] = 0.f;
        #pragma unroll
        for (int k = 0; k < K_; ++k) {
            float av = sA[t + k];
            const float4* fp = reinterpret_cast<const float4*>(&sFG[k * 16]);
            float4 x0 = fp[0], x1 = fp[1], x2 = fp[2], x3 = fp[3];
            fg[0]  += x0.x * av; fg[1]  += x0.y * av; fg[2]  += x0.z * av; fg[3]  += x0.w * av;
            fg[4]  += x1.x * av; fg[5]  += x1.y * av; fg[6]  += x1.z * av; fg[7]  += x1.w * av;
            fg[8]  += x2.x * av; fg[9]  += x2.y * av; fg[10] += x2.z * av; fg[11] += x2.w * av;
            fg[12] += x3.x * av; fg[13] += x3.y * av; fg[14] += x3.z * av; fg[15] += x3.w * av;
        }
        float accQ = 0.f;
        const int d0 = qq * 32;
        #pragma unroll 4
        for (int dd = 0; dd < 32; ++dd) {
            const float4* up = reinterpret_cast<const float4*>(&sUT[(d0 + dd) * 16]);
            float4 u0 = up[0], u1 = up[1], u2 = up[2], u3 = up[3];
            float s = sTb[d0 + dd];
            s += u0.x * fg[0]  + u0.y * fg[1]  + u0.z * fg[2]  + u0.w * fg[3];
            s += u1.x * fg[4]  + u1.y * fg[5]  + u1.z * fg[6]  + u1.w * fg[7];
            s += u2.x * fg[8]  + u2.y * fg[9]  + u2.z * fg[10] + u2.w * fg[11];
            s += u3.x * fg[12] + u3.y * fg[13] + u3.z * fg[14] + u3.w * fg[15];
            accQ += sV[d0 + dd] * fast_tanh(s);
        }
        sQ[qq * CHK + t] = accQ;
    }
    __syncthreads();

    // ---- chunk-local online softmax (wave 0 only: tid < 64) ----
    if (tid < CHK) {
        const int tg = t0 + tid;
        float e = -1e30f;
        if (tg < T_ && !mask[b * T_ + tg]) {
            float pp = 0.f;
            #pragma unroll
            for (int k = 0; k < PL_; ++k) pp += sPr[k] * sA[tid + k];
            e = sQ[tid] + sQ[CHK + tid] + sQ[2 * CHK + tid] + sQ[3 * CHK + tid]
              + __logf(fmaxf(pp, 1e-6f));
        }
        float m = e;
        #pragma unroll
        for (int off = 32; off > 0; off >>= 1) m = fmaxf(m, __shfl_xor(m, off));
        float pv = (e > -1e29f) ? __expf(e - m) : 0.f;
        sE[tid] = pv;
        if (tg < T_) wout[b * T_ + tg] = pv;
        float ss = pv;
        #pragma unroll
        for (int off = 32; off > 0; off >>= 1) ss += __shfl_xor(ss, off);
        if (tid == 0) { mred[b * NCHK + chunk] = m; sred[b * NCHK + chunk] = ss; }
    }
    __syncthreads();

    // ---- stream memory slice, accumulate partial context ----
    {
        const int col = tid & 127, rp = tid >> 7;
        const vf4* m4 = reinterpret_cast<const vf4*>(mem + ((size_t)(b * T_ + t0)) * EMB_);
        vf4 acc = {0.f, 0.f, 0.f, 0.f};
        for (int tt = rp; tt < nvalid; tt += 2) {
            float wv = sE[tt];
            vf4 mv = __builtin_nontemporal_load(m4 + (size_t)tt * (EMB_ / 4) + col);
            acc += wv * mv;
        }
        sCtx4[rp][col] = acc;
    }
    __syncthreads();
    if (tid < EMB_ / 4) {
        vf4 r = sCtx4[0][tid];
        r += sCtx4[1][tid];
        reinterpret_cast<vf4*>(ctxp + ((size_t)(b * NCHK + chunk)) * EMB_)[tid] = r;
    }
}

// ---- kernel 3: combine partials -> context + normalized weights ----
__global__ __launch_bounds__(256) void k_final(
    const float* __restrict__ mred, const float* __restrict__ sred,
    const float* __restrict__ ctxp, float* __restrict__ wout,
    float* __restrict__ out_ctx)
{
    __shared__ float sM[NCHK], sS[NCHK], sAl[NCHK];
    const int b = blockIdx.x, tid = threadIdx.x;
    if (tid < NCHK) { sM[tid] = mred[b * NCHK + tid]; sS[tid] = sred[b * NCHK + tid]; }
    __syncthreads();
    float M = -1e30f;
    #pragma unroll
    for (int i = 0; i < NCHK; ++i) M = fmaxf(M, sM[i]);
    float S = 0.f;
    #pragma unroll
    for (int i = 0; i < NCHK; ++i) S += sS[i] * __expf(sM[i] - M);
    const float inv = 1.0f / S;
    if (tid < NCHK) sAl[tid] = __expf(sM[tid] - M) * inv;
    __syncthreads();
    if (tid < EMB_ / 4) {
        vf4 acc = {0.f, 0.f, 0.f, 0.f};
        const vf4* cp = reinterpret_cast<const vf4*>(ctxp + (size_t)b * NCHK * EMB_);
        #pragma unroll
        for (int i = 0; i < NCHK; ++i) acc += sAl[i] * cp[i * (EMB_ / 4) + tid];
        reinterpret_cast<vf4*>(out_ctx + b * EMB_)[tid] = acc;
    }
    for (int t = tid; t < T_; t += 256) wout[b * T_ + t] *= sAl[t >> 6];  // t/CHK
}

extern "C" void kernel_launch(void* const* d_in, const int* in_sizes, int n_in,
                              void* d_out, int out_size, void* d_ws, size_t ws_size,
                              hipStream_t stream)
{
    const float* q    = (const float*)d_in[0];
    const float* mem  = (const float*)d_in[1];
    const float* a    = (const float*)d_in[2];
    const unsigned char* mask = (const unsigned char*)d_in[3];
    const float* Ww = (const float*)d_in[4];
    const float* Wb = (const float*)d_in[5];
    const float* Vw = (const float*)d_in[6];
    const float* Fw = (const float*)d_in[7];
    const float* Uw = (const float*)d_in[8];
    const float* Tw = (const float*)d_in[9];
    const float* Tb = (const float*)d_in[10];
    const float* vw = (const float*)d_in[11];
    const float* P  = (const float*)d_in[12];

    float* out_ctx = (float*)d_out;           // [64*512]
    float* out_w   = out_ctx + B_ * EMB_;     // [64*2000]

    float* G    = (float*)d_ws;               // [64*168]
    float* mred = G + B_ * GSZ;               // [64*32]
    float* sred = mred + B_ * NCHK;           // [64*32]
    float* ctxp = sred + B_ * NCHK;           // [64*32*512] = 4 MB

    k_gen_dyn<<<B_, 256, 0, stream>>>(q, Ww, Wb, Vw, G);
    k_fused<<<dim3(B_, NCHK), 256, 0, stream>>>(a, G, Fw, Uw, Tw, Tb, vw, P,
                                                mask, mem, out_w, ctxp, mred, sred);
    k_final<<<B_, 256, 0, stream>>>(mred, sred, ctxp, out_w, out_ctx);
}

// Round 4
// 99.664 us; speedup vs baseline: 1.1685x; 1.1685x over previous
//
#include <hip/hip_runtime.h>

#define B_   64
#define T_   2000
#define RNN_ 1024
#define EMB_ 512
#define ATT_ 128
#define CH_  8
#define K_   21
#define PL_  11
#define GSZ  168   // CH_*K_
#define ECHK 256   // energy chunk (8 per batch)
#define NEC  8
#define CCHK 64    // ctx chunk (32 per batch)
#define NCC  32

typedef float vf4 __attribute__((ext_vector_type(4)));

__device__ __forceinline__ float fast_tanh(float x) {
    float ax = fabsf(x);
    float e  = __expf(2.0f * ax);
    float t  = 1.0f - 2.0f / (e + 1.0f);
    return copysignf(t, x);
}

// ---- kernel 1: G = tanh(q @ W_w^T + W_b) @ V_w^T  -> [B,168] ----
__global__ __launch_bounds__(256) void k_gen_dyn(
    const float* __restrict__ q, const float* __restrict__ Ww,
    const float* __restrict__ Wb, const float* __restrict__ Vw,
    float* __restrict__ G)
{
    __shared__ float sq[RNN_];
    __shared__ float part[256];
    __shared__ float sh[ATT_];
    const int b = blockIdx.x, tid = threadIdx.x;
    for (int i = tid; i < RNN_; i += 256) sq[i] = q[b * RNN_ + i];
    __syncthreads();
    {
        const int row = tid & 127, half = tid >> 7;        // 2-way K split
        const float4* wr = reinterpret_cast<const float4*>(Ww + row * RNN_ + half * (RNN_ / 2));
        const float4* qr = reinterpret_cast<const float4*>(sq + half * (RNN_ / 2));
        float acc = 0.f;
        #pragma unroll 8
        for (int i = 0; i < RNN_ / 8; ++i) {
            float4 w4 = wr[i], q4 = qr[i];
            acc += w4.x * q4.x + w4.y * q4.y + w4.z * q4.z + w4.w * q4.w;
        }
        part[tid] = acc;
    }
    __syncthreads();
    if (tid < ATT_) sh[tid] = fast_tanh(part[tid] + part[tid + 128] + Wb[tid]);
    __syncthreads();
    for (int o = tid; o < GSZ; o += 256) {
        const float4* vr = reinterpret_cast<const float4*>(Vw + o * ATT_);
        const float4* hr = reinterpret_cast<const float4*>(sh);
        float acc = 0.f;
        #pragma unroll 8
        for (int i = 0; i < ATT_ / 4; ++i) {
            float4 v4 = vr[i], h4 = hr[i];
            acc += v4.x * h4.x + v4.y * h4.y + v4.z * h4.z + v4.w * h4.w;
        }
        G[b * GSZ + o] = acc;
    }
}

// ---- kernel 2: energy + chunk-local max/sum -> p = exp(e - m_c), (m_c, s_c) ----
__global__ __launch_bounds__(256) void k_energy(
    const float* __restrict__ a,  const float* __restrict__ G,
    const float* __restrict__ Fw, const float* __restrict__ Uw,
    const float* __restrict__ Tw, const float* __restrict__ Tb,
    const float* __restrict__ vw, const float* __restrict__ P,
    const unsigned char* __restrict__ mask,
    float* __restrict__ pout, float* __restrict__ mred, float* __restrict__ sred)
{
    __shared__ float sA[ECHK + K_ - 1];  // 276 window
    __shared__ float sFG[K_ * 16];       // [k][16]: c<8 = F_w[c][k], c>=8 = G[b][(c-8)*21+k]
    __shared__ float sUT[ATT_ * 16];     // [d][16]: c<8 = U_w[d][c], c>=8 = T_w[d][c-8]
    __shared__ float sTb[ATT_], sV[ATT_], sPr[PL_];
    __shared__ float red[4];
    const int b = blockIdx.x, chunk = blockIdx.y, tid = threadIdx.x;
    const int t0 = chunk * ECHK;
    const int base = t0 - (K_ - 1) / 2;  // t0 - 10

    for (int j = tid; j < ECHK + K_ - 1; j += 256) {
        int idx = base + j;
        sA[j] = (idx >= 0 && idx < T_) ? a[b * T_ + idx] : 0.f;
    }
    for (int j = tid; j < 2 * GSZ; j += 256) {
        if (j < GSZ) sFG[(j % K_) * 16 + (j / K_)] = Fw[j];
        else { int jj = j - GSZ; sFG[(jj % K_) * 16 + 8 + (jj / K_)] = G[b * GSZ + jj]; }
    }
    for (int j = tid; j < ATT_ * CH_; j += 256) {
        int d = j >> 3, c = j & 7;
        sUT[d * 16 + c]     = Uw[j];
        sUT[d * 16 + 8 + c] = Tw[j];
    }
    if (tid < ATT_) { sTb[tid] = Tb[tid]; sV[tid] = vw[tid]; }
    if (tid < PL_)  sPr[tid] = P[tid];
    __syncthreads();

    const int t = t0 + tid;
    const bool valid = (t < T_) && !mask[b * T_ + min(t, T_ - 1)];

    float fg[16];
    #pragma unroll
    for (int i = 0; i < 16; ++i) fg[i] = 0.f;
    #pragma unroll
    for (int k = 0; k < K_; ++k) {
        float av = sA[tid + k];
        const float4* fp = reinterpret_cast<const float4*>(&sFG[k * 16]);
        float4 x0 = fp[0], x1 = fp[1], x2 = fp[2], x3 = fp[3];
        fg[0]  += x0.x * av; fg[1]  += x0.y * av; fg[2]  += x0.z * av; fg[3]  += x0.w * av;
        fg[4]  += x1.x * av; fg[5]  += x1.y * av; fg[6]  += x1.z * av; fg[7]  += x1.w * av;
        fg[8]  += x2.x * av; fg[9]  += x2.y * av; fg[10] += x2.z * av; fg[11] += x2.w * av;
        fg[12] += x3.x * av; fg[13] += x3.y * av; fg[14] += x3.z * av; fg[15] += x3.w * av;
    }
    float pp = 0.f;
    #pragma unroll
    for (int k = 0; k < PL_; ++k) pp += sPr[k] * sA[tid + k];

    float acc = 0.f;
    #pragma unroll 4
    for (int d = 0; d < ATT_; ++d) {
        const float4* up = reinterpret_cast<const float4*>(&sUT[d * 16]);
        float4 u0 = up[0], u1 = up[1], u2 = up[2], u3 = up[3];
        float s = sTb[d];
        s += u0.x * fg[0]  + u0.y * fg[1]  + u0.z * fg[2]  + u0.w * fg[3];
        s += u1.x * fg[4]  + u1.y * fg[5]  + u1.z * fg[6]  + u1.w * fg[7];
        s += u2.x * fg[8]  + u2.y * fg[9]  + u2.z * fg[10] + u2.w * fg[11];
        s += u3.x * fg[12] + u3.y * fg[13] + u3.z * fg[14] + u3.w * fg[15];
        acc += sV[d] * fast_tanh(s);
    }
    float e = valid ? (acc + __logf(fmaxf(pp, 1e-6f))) : -1e30f;

    // block max
    float m = e;
    #pragma unroll
    for (int off = 32; off > 0; off >>= 1) m = fmaxf(m, __shfl_xor(m, off));
    if ((tid & 63) == 0) red[tid >> 6] = m;
    __syncthreads();
    const float Mc = fmaxf(fmaxf(red[0], red[1]), fmaxf(red[2], red[3]));
    __syncthreads();
    // p and block sum
    float pv = valid ? __expf(e - Mc) : 0.f;
    if (t < T_) pout[b * T_ + t] = pv;
    float ssum = pv;
    #pragma unroll
    for (int off = 32; off > 0; off >>= 1) ssum += __shfl_xor(ssum, off);
    if ((tid & 63) == 0) red[tid >> 6] = ssum;
    __syncthreads();
    if (tid == 0) {
        mred[b * NEC + chunk] = Mc;
        sred[b * NEC + chunk] = red[0] + red[1] + red[2] + red[3];
    }
}

// ---- kernel 3: normalize weights + stream memory + atomic context ----
__global__ __launch_bounds__(256) void k_ctx(
    const float* __restrict__ mred, const float* __restrict__ sred,
    const float* __restrict__ mem, float* __restrict__ w,
    float* __restrict__ out)
{
    __shared__ float sw[CCHK];
    __shared__ vf4 sCtx[2][EMB_ / 4];
    const int b = blockIdx.x, chunk = blockIdx.y, tid = threadIdx.x;
    const int t0 = chunk * CCHK;
    const int nvalid = min(CCHK, T_ - t0);

    // alpha from the 8 energy-chunk (m,s) pairs
    float mv[NEC], sv[NEC];
    {
        const float4* mp = reinterpret_cast<const float4*>(mred + b * NEC);
        const float4* sp = reinterpret_cast<const float4*>(sred + b * NEC);
        float4 m0 = mp[0], m1 = mp[1], s0 = sp[0], s1 = sp[1];
        mv[0]=m0.x; mv[1]=m0.y; mv[2]=m0.z; mv[3]=m0.w;
        mv[4]=m1.x; mv[5]=m1.y; mv[6]=m1.z; mv[7]=m1.w;
        sv[0]=s0.x; sv[1]=s0.y; sv[2]=s0.z; sv[3]=s0.w;
        sv[4]=s1.x; sv[5]=s1.y; sv[6]=s1.z; sv[7]=s1.w;
    }
    float M = mv[0];
    #pragma unroll
    for (int i = 1; i < NEC; ++i) M = fmaxf(M, mv[i]);
    float S = 0.f;
    #pragma unroll
    for (int i = 0; i < NEC; ++i) S += sv[i] * __expf(mv[i] - M);
    const float scale = __expf(mv[chunk >> 2] - M) / S;

    if (tid < CCHK) {
        const int t = t0 + tid;
        float wv = 0.f;
        if (t < T_) {
            wv = w[b * T_ + t] * scale;
            w[b * T_ + t] = wv;
        }
        sw[tid] = wv;
    }
    __syncthreads();

    const int col = tid & 127, rp = tid >> 7;
    const vf4* m4 = reinterpret_cast<const vf4*>(mem + ((size_t)(b * T_ + t0)) * EMB_);
    vf4 acc = {0.f, 0.f, 0.f, 0.f};
    if (nvalid == CCHK) {
        #pragma unroll 8
        for (int tt = rp; tt < CCHK; tt += 2) {
            float wv = sw[tt];
            vf4 mvv = __builtin_nontemporal_load(m4 + (size_t)tt * (EMB_ / 4) + col);
            acc += wv * mvv;
        }
    } else {
        for (int tt = rp; tt < nvalid; tt += 2) {
            float wv = sw[tt];
            vf4 mvv = __builtin_nontemporal_load(m4 + (size_t)tt * (EMB_ / 4) + col);
            acc += wv * mvv;
        }
    }
    sCtx[rp][col] = acc;
    __syncthreads();
    if (tid < EMB_ / 4) {
        vf4 r = sCtx[0][tid];
        r += sCtx[1][tid];
        float* op = out + b * EMB_ + tid * 4;
        atomicAdd(op + 0, r.x); atomicAdd(op + 1, r.y);
        atomicAdd(op + 2, r.z); atomicAdd(op + 3, r.w);
    }
}

extern "C" void kernel_launch(void* const* d_in, const int* in_sizes, int n_in,
                              void* d_out, int out_size, void* d_ws, size_t ws_size,
                              hipStream_t stream)
{
    const float* q    = (const float*)d_in[0];
    const float* mem  = (const float*)d_in[1];
    const float* a    = (const float*)d_in[2];
    const unsigned char* mask = (const unsigned char*)d_in[3];
    const float* Ww = (const float*)d_in[4];
    const float* Wb = (const float*)d_in[5];
    const float* Vw = (const float*)d_in[6];
    const float* Fw = (const float*)d_in[7];
    const float* Uw = (const float*)d_in[8];
    const float* Tw = (const float*)d_in[9];
    const float* Tb = (const float*)d_in[10];
    const float* vw = (const float*)d_in[11];
    const float* P  = (const float*)d_in[12];

    float* out_ctx = (float*)d_out;           // [64*512]
    float* out_w   = out_ctx + B_ * EMB_;     // [64*2000]

    float* G    = (float*)d_ws;               // [64*168]
    float* mred = G + B_ * GSZ;               // [64*8]
    float* sred = mred + B_ * NEC;            // [64*8]

    hipMemsetAsync(out_ctx, 0, B_ * EMB_ * sizeof(float), stream);
    k_gen_dyn<<<B_, 256, 0, stream>>>(q, Ww, Wb, Vw, G);
    k_energy<<<dim3(B_, NEC), 256, 0, stream>>>(a, G, Fw, Uw, Tw, Tb, vw, P,
                                                mask, out_w, mred, sred);
    k_ctx<<<dim3(B_, NCC), 256, 0, stream>>>(mred, sred, mem, out_w, out_ctx);
}

// Round 5
// 94.223 us; speedup vs baseline: 1.2360x; 1.0577x over previous
//
#include <hip/hip_runtime.h>

#define B_   64
#define T_   2000
#define RNN_ 1024
#define EMB_ 512
#define ATT_ 128
#define CH_  8
#define K_   21
#define PL_  11
#define GSZ  168   // CH_*K_
#define ECHK 128   // energy chunk (16 per batch)
#define NEC  16
#define CCHK 64    // ctx chunk (32 per batch)
#define NCC  32

typedef float vf4 __attribute__((ext_vector_type(4)));

__device__ __forceinline__ float fast_tanh(float x) {
    float ax = fabsf(x);
    float e  = __expf(2.0f * ax);
    float t  = 1.0f - 2.0f / (e + 1.0f);
    return copysignf(t, x);
}

// ---- kernel 1: zero out_ctx + G = tanh(q @ W_w^T + W_b) @ V_w^T ----
__global__ __launch_bounds__(256) void k_gen_dyn(
    const float* __restrict__ q, const float* __restrict__ Ww,
    const float* __restrict__ Wb, const float* __restrict__ Vw,
    float* __restrict__ G, float* __restrict__ out_ctx)
{
    __shared__ float sq[RNN_];
    __shared__ float part[256];
    __shared__ float sh[ATT_];
    const int b = blockIdx.x, tid = threadIdx.x;
    for (int i = tid; i < EMB_; i += 256) out_ctx[b * EMB_ + i] = 0.f;
    for (int i = tid; i < RNN_; i += 256) sq[i] = q[b * RNN_ + i];
    __syncthreads();
    {
        const int row = tid & 127, half = tid >> 7;        // 2-way K split
        const float4* wr = reinterpret_cast<const float4*>(Ww + row * RNN_ + half * (RNN_ / 2));
        const float4* qr = reinterpret_cast<const float4*>(sq + half * (RNN_ / 2));
        float acc = 0.f;
        #pragma unroll 8
        for (int i = 0; i < RNN_ / 8; ++i) {
            float4 w4 = wr[i], q4 = qr[i];
            acc += w4.x * q4.x + w4.y * q4.y + w4.z * q4.z + w4.w * q4.w;
        }
        part[tid] = acc;
    }
    __syncthreads();
    if (tid < ATT_) sh[tid] = fast_tanh(part[tid] + part[tid + 128] + Wb[tid]);
    __syncthreads();
    for (int o = tid; o < GSZ; o += 256) {
        const float4* vr = reinterpret_cast<const float4*>(Vw + o * ATT_);
        const float4* hr = reinterpret_cast<const float4*>(sh);
        float acc = 0.f;
        #pragma unroll 8
        for (int i = 0; i < ATT_ / 4; ++i) {
            float4 v4 = vr[i], h4 = hr[i];
            acc += v4.x * h4.x + v4.y * h4.y + v4.z * h4.z + v4.w * h4.w;
        }
        G[b * GSZ + o] = acc;
    }
}

// ---- kernel 2: energy (2-way d-split) + chunk max/sum -> p = exp(e - m_c) ----
__global__ __launch_bounds__(256) void k_energy(
    const float* __restrict__ a,  const float* __restrict__ G,
    const float* __restrict__ Fw, const float* __restrict__ Uw,
    const float* __restrict__ Tw, const float* __restrict__ Tb,
    const float* __restrict__ vw, const float* __restrict__ P,
    const unsigned char* __restrict__ mask,
    float* __restrict__ pout, float* __restrict__ mred, float* __restrict__ sred)
{
    __shared__ float sA[ECHK + K_ - 1];  // 148 window
    __shared__ float sFG[K_ * 16];       // [k][16]: c<8 = F_w[c][k], c>=8 = G[b][(c-8)*21+k]
    __shared__ float sUT[ATT_ * 16];     // [d][16]: c<8 = U_w[d][c], c>=8 = T_w[d][c-8]
    __shared__ float sTb[ATT_], sV[ATT_], sPr[PL_];
    __shared__ float sQ[2 * ECHK];       // [h][t] half-partials of MLP output
    __shared__ float red[4];
    const int b = blockIdx.x, chunk = blockIdx.y, tid = threadIdx.x;
    const int t0 = chunk * ECHK;
    const int base = t0 - (K_ - 1) / 2;  // t0 - 10
    const int tloc = tid & (ECHK - 1);
    const int h = tid >> 7;

    for (int j = tid; j < ECHK + K_ - 1; j += 256) {
        int idx = base + j;
        sA[j] = (idx >= 0 && idx < T_) ? a[b * T_ + idx] : 0.f;
    }
    for (int j = tid; j < 2 * GSZ; j += 256) {
        if (j < GSZ) sFG[(j % K_) * 16 + (j / K_)] = Fw[j];
        else { int jj = j - GSZ; sFG[(jj % K_) * 16 + 8 + (jj / K_)] = G[b * GSZ + jj]; }
    }
    for (int j = tid; j < ATT_ * CH_; j += 256) {
        int d = j >> 3, c = j & 7;
        sUT[d * 16 + c]     = Uw[j];
        sUT[d * 16 + 8 + c] = Tw[j];
    }
    if (tid < ATT_) { sTb[tid] = Tb[tid]; sV[tid] = vw[tid]; }
    if (tid < PL_)  sPr[tid] = P[tid];
    __syncthreads();

    // conv features (redundant across halves, cheap)
    float fg[16];
    #pragma unroll
    for (int i = 0; i < 16; ++i) fg[i] = 0.f;
    #pragma unroll
    for (int k = 0; k < K_; ++k) {
        float av = sA[tloc + k];
        const float4* fp = reinterpret_cast<const float4*>(&sFG[k * 16]);
        float4 x0 = fp[0], x1 = fp[1], x2 = fp[2], x3 = fp[3];
        fg[0]  += x0.x * av; fg[1]  += x0.y * av; fg[2]  += x0.z * av; fg[3]  += x0.w * av;
        fg[4]  += x1.x * av; fg[5]  += x1.y * av; fg[6]  += x1.z * av; fg[7]  += x1.w * av;
        fg[8]  += x2.x * av; fg[9]  += x2.y * av; fg[10] += x2.z * av; fg[11] += x2.w * av;
        fg[12] += x3.x * av; fg[13] += x3.y * av; fg[14] += x3.z * av; fg[15] += x3.w * av;
    }

    // MLP: this thread handles dims [h*64, h*64+64)
    float accQ = 0.f;
    const int d0 = h * 64;
    #pragma unroll 4
    for (int dd = 0; dd < 64; ++dd) {
        const int d = d0 + dd;
        const float4* up = reinterpret_cast<const float4*>(&sUT[d * 16]);
        float4 u0 = up[0], u1 = up[1], u2 = up[2], u3 = up[3];
        float s0 = u0.x * fg[0]  + u0.y * fg[1]  + u0.z * fg[2]  + u0.w * fg[3];
        float s1 = u1.x * fg[4]  + u1.y * fg[5]  + u1.z * fg[6]  + u1.w * fg[7];
        float s2 = u2.x * fg[8]  + u2.y * fg[9]  + u2.z * fg[10] + u2.w * fg[11];
        float s3 = u3.x * fg[12] + u3.y * fg[13] + u3.z * fg[14] + u3.w * fg[15];
        float s = (sTb[d] + s0) + (s1 + s2) + s3;
        accQ += sV[d] * fast_tanh(s);
    }
    sQ[h * ECHK + tloc] = accQ;
    __syncthreads();

    // energies for tid < 128; others carry -inf through the block reduction
    float e = -1e30f;
    const int t = t0 + tid;
    if (tid < ECHK) {
        const bool valid = (t < T_) && !mask[b * T_ + min(t, T_ - 1)];
        if (valid) {
            float pp = 0.f;
            #pragma unroll
            for (int k = 0; k < PL_; ++k) pp += sPr[k] * sA[tid + k];
            e = sQ[tid] + sQ[ECHK + tid] + __logf(fmaxf(pp, 1e-6f));
        }
    }
    float m = e;
    #pragma unroll
    for (int off = 32; off > 0; off >>= 1) m = fmaxf(m, __shfl_xor(m, off));
    if ((tid & 63) == 0) red[tid >> 6] = m;
    __syncthreads();
    const float Mc = fmaxf(fmaxf(red[0], red[1]), fmaxf(red[2], red[3]));
    __syncthreads();
    float pv = (e > -1e29f) ? __expf(e - Mc) : 0.f;
    if (tid < ECHK && t < T_) pout[b * T_ + t] = pv;
    float ssum = pv;
    #pragma unroll
    for (int off = 32; off > 0; off >>= 1) ssum += __shfl_xor(ssum, off);
    if ((tid & 63) == 0) red[tid >> 6] = ssum;
    __syncthreads();
    if (tid == 0) {
        mred[b * NEC + chunk] = Mc;
        sred[b * NEC + chunk] = red[0] + red[1] + red[2] + red[3];
    }
}

// ---- kernel 3: normalize weights + stream memory + atomic context ----
__global__ __launch_bounds__(256, 8) void k_ctx(
    const float* __restrict__ mred, const float* __restrict__ sred,
    const float* __restrict__ mem, float* __restrict__ w,
    float* __restrict__ out)
{
    __shared__ float sw_[CCHK];
    __shared__ vf4 sCtx[2][EMB_ / 4];
    const int b = blockIdx.x, chunk = blockIdx.y, tid = threadIdx.x;
    const int t0 = chunk * CCHK;
    const int nvalid = min(CCHK, T_ - t0);

    // global (M, S) from the 16 energy-chunk pairs (vector form, no indexed array)
    const float4* mp = reinterpret_cast<const float4*>(mred + b * NEC);
    const float4* sp = reinterpret_cast<const float4*>(sred + b * NEC);
    float4 m0 = mp[0], m1 = mp[1], m2 = mp[2], m3 = mp[3];
    float M = fmaxf(fmaxf(fmaxf(m0.x, m0.y), fmaxf(m0.z, m0.w)),
             fmaxf(fmaxf(fmaxf(m1.x, m1.y), fmaxf(m1.z, m1.w)),
             fmaxf(fmaxf(fmaxf(m2.x, m2.y), fmaxf(m2.z, m2.w)),
                   fmaxf(fmaxf(m3.x, m3.y), fmaxf(m3.z, m3.w)))));
    float4 s0 = sp[0], s1 = sp[1], s2 = sp[2], s3 = sp[3];
    float S = s0.x * __expf(m0.x - M) + s0.y * __expf(m0.y - M)
            + s0.z * __expf(m0.z - M) + s0.w * __expf(m0.w - M)
            + s1.x * __expf(m1.x - M) + s1.y * __expf(m1.y - M)
            + s1.z * __expf(m1.z - M) + s1.w * __expf(m1.w - M)
            + s2.x * __expf(m2.x - M) + s2.y * __expf(m2.y - M)
            + s2.z * __expf(m2.z - M) + s2.w * __expf(m2.w - M)
            + s3.x * __expf(m3.x - M) + s3.y * __expf(m3.y - M)
            + s3.z * __expf(m3.z - M) + s3.w * __expf(m3.w - M);
    const float scale = __expf(mred[b * NEC + (chunk >> 1)] - M) / S;

    if (tid < CCHK) {
        const int t = t0 + tid;
        float wv = 0.f;
        if (t < T_) {
            wv = w[b * T_ + t] * scale;
            w[b * T_ + t] = wv;
        }
        sw_[tid] = wv;
    }
    __syncthreads();

    const int col = tid & 127, rp = tid >> 7;
    const vf4* m4 = reinterpret_cast<const vf4*>(mem + ((size_t)(b * T_ + t0)) * EMB_);
    vf4 acc = {0.f, 0.f, 0.f, 0.f};
    if (nvalid == CCHK) {
        #pragma unroll 8
        for (int tt = rp; tt < CCHK; tt += 2) {
            float wv = sw_[tt];
            vf4 mvv = m4[(size_t)tt * (EMB_ / 4) + col];
            acc += wv * mvv;
        }
    } else {
        for (int tt = rp; tt < nvalid; tt += 2) {
            float wv = sw_[tt];
            vf4 mvv = m4[(size_t)tt * (EMB_ / 4) + col];
            acc += wv * mvv;
        }
    }
    sCtx[rp][col] = acc;
    __syncthreads();
    if (tid < EMB_ / 4) {
        vf4 r = sCtx[0][tid];
        r += sCtx[1][tid];
        float* op = out + b * EMB_ + tid * 4;
        atomicAdd(op + 0, r.x); atomicAdd(op + 1, r.y);
        atomicAdd(op + 2, r.z); atomicAdd(op + 3, r.w);
    }
}

extern "C" void kernel_launch(void* const* d_in, const int* in_sizes, int n_in,
                              void* d_out, int out_size, void* d_ws, size_t ws_size,
                              hipStream_t stream)
{
    const float* q    = (const float*)d_in[0];
    const float* mem  = (const float*)d_in[1];
    const float* a    = (const float*)d_in[2];
    const unsigned char* mask = (const unsigned char*)d_in[3];
    const float* Ww = (const float*)d_in[4];
    const float* Wb = (const float*)d_in[5];
    const float* Vw = (const float*)d_in[6];
    const float* Fw = (const float*)d_in[7];
    const float* Uw = (const float*)d_in[8];
    const float* Tw = (const float*)d_in[9];
    const float* Tb = (const float*)d_in[10];
    const float* vw = (const float*)d_in[11];
    const float* P  = (const float*)d_in[12];

    float* out_ctx = (float*)d_out;           // [64*512]
    float* out_w   = out_ctx + B_ * EMB_;     // [64*2000]

    float* G    = (float*)d_ws;               // [64*168]
    float* mred = G + B_ * GSZ;               // [64*16]
    float* sred = mred + B_ * NEC;            // [64*16]

    k_gen_dyn<<<B_, 256, 0, stream>>>(q, Ww, Wb, Vw, G, out_ctx);
    k_energy<<<dim3(B_, NEC), 256, 0, stream>>>(a, G, Fw, Uw, Tw, Tb, vw, P,
                                                mask, out_w, mred, sred);
    k_ctx<<<dim3(B_, NCC), 256, 0, stream>>>(mred, sred, mem, out_w, out_ctx);
}